// Round 4
// baseline (606.663 us; speedup 1.0000x reference)
//
#include <hip/hip_runtime.h>

#define C_CH  128
#define NP    32768
#define K_PWL 20
#define LAT   8
#define HID   8
#define P1PTS 4                 // points per thread in pass1t
#define QBLK  (NP / (256 * P1PTS))   // 32 partial-blocks per channel

__device__ __forceinline__ float fast_tanh(float x) {
    float e = __expf(2.0f * x);
    return fmaf(-2.0f, __builtin_amdgcn_rcpf(e + 1.0f), 1.0f);
}

// 8->8(tanh)->1(tanh) MLP; W layout: W1[64], b1[8]@64, W2[8]@72, b2@80.
// Identical op order to the verified kernel -> identical numerics.
__device__ __forceinline__ float mlp_eval(const float* W, float4 r0, float4 r1) {
    float acc = W[80];
    #pragma unroll
    for (int j = 0; j < HID; j++) {
        float hh = W[64 + j];
        hh = fmaf(r0.x, W[0 * 8 + j], hh);
        hh = fmaf(r0.y, W[1 * 8 + j], hh);
        hh = fmaf(r0.z, W[2 * 8 + j], hh);
        hh = fmaf(r0.w, W[3 * 8 + j], hh);
        hh = fmaf(r1.x, W[4 * 8 + j], hh);
        hh = fmaf(r1.y, W[5 * 8 + j], hh);
        hh = fmaf(r1.z, W[6 * 8 + j], hh);
        hh = fmaf(r1.w, W[7 * 8 + j], hh);
        acc = fmaf(fast_tanh(hh), W[72 + j], acc);
    }
    return fast_tanh(acc);
}

// grid: (QBLK, C_CH). Block (q,c): points [q*1024, q*1024+1024) of channel c.
// Contiguous reads; stores to blocked-transpose [NP/32][C][32]; ATOMIC-FREE
// partials (no init kernel needed): pminB/pmaxB/psum indexed by c*QBLK+q.
// __launch_bounds__(256,4): empirical hipcc law VGPR budget = 256/arg2 = 64
// ((256,8) gave budget 32 -> wholesale spill, 384 MB scratch writes in r3).
// #pragma unroll 1 keeps the live set to one point's staging (~45 regs).
__global__ __launch_bounds__(256, 4)
void pass1t(const float* __restrict__ zx, const float* __restrict__ ze,
            const float* __restrict__ Wx1, const float* __restrict__ bx1,
            const float* __restrict__ Wx2, const float* __restrict__ bx2,
            const float* __restrict__ We1, const float* __restrict__ be1,
            const float* __restrict__ We2, const float* __restrict__ be2,
            float* __restrict__ xtile, float* __restrict__ etile,
            float* __restrict__ pminB, float* __restrict__ pmaxB,
            double* __restrict__ psum) {
    // weights in LDS: Wx1[64] bx1[8] Wx2[8] bx2[1] We1[64] be1[8] We2[8] be2[1]
    __shared__ float sw[162];
    int t = threadIdx.x;
    if (t < 64)       sw[t] = Wx1[t];
    else if (t < 72)  sw[t] = bx1[t - 64];
    else if (t < 80)  sw[t] = Wx2[t - 72];
    else if (t == 80) sw[80] = bx2[0];
    else if (t < 145) sw[t] = We1[t - 81];
    else if (t < 153) sw[t] = be1[t - 145];
    else if (t < 161) sw[t] = We2[t - 153];
    else if (t == 161) sw[161] = be2[0];
    __syncthreads();

    int q = blockIdx.x;
    int c = blockIdx.y;
    int n0 = q * (256 * P1PTS) + t;
    size_t row = (size_t)c * NP;
    const float4* zx4 = (const float4*)(zx + row * LAT);
    const float4* ze4 = (const float4*)(ze + row * LAT);
    int cbase = c * 32;

    float mn = 3.0e38f, mx = -3.0e38f, s = 0.f, s2 = 0.f;
    #pragma unroll 1
    for (int k = 0; k < P1PTS; k++) {
        int n = n0 + k * 256;
        float4 a0 = zx4[2 * n], a1 = zx4[2 * n + 1];
        float4 e0 = ze4[2 * n], e1 = ze4[2 * n + 1];
        float xv = mlp_eval(sw, a0, a1);
        float ev = mlp_eval(sw + 81, e0, e1);
        int addr = (n >> 5) * (C_CH * 32) + cbase + (n & 31);
        xtile[addr] = xv;
        etile[addr] = ev;
        mn = fminf(mn, xv); mx = fmaxf(mx, xv);
        s += ev; s2 = fmaf(ev, ev, s2);
    }

    #pragma unroll
    for (int o = 32; o > 0; o >>= 1) {
        mn = fminf(mn, __shfl_down(mn, o));
        mx = fmaxf(mx, __shfl_down(mx, o));
        s += __shfl_down(s, o);
        s2 += __shfl_down(s2, o);
    }
    __shared__ float rmn[4], rmx[4], rs[4], rs2[4];
    int wave = t >> 6, lane = t & 63;
    if (lane == 0) { rmn[wave] = mn; rmx[wave] = mx; rs[wave] = s; rs2[wave] = s2; }
    __syncthreads();
    if (t == 0) {
        for (int w = 1; w < 4; w++) {
            mn = fminf(mn, rmn[w]); mx = fmaxf(mx, rmx[w]);
        }
        int slot = c * QBLK + q;
        pminB[slot] = mn;
        pmaxB[slot] = mx;
        psum[2 * slot]     = (double)rs[0] + (double)rs[1] + (double)rs[2] + (double)rs[3];
        psum[2 * slot + 1] = (double)rs2[0] + (double)rs2[1] + (double)rs2[2] + (double)rs2[3];
    }
}

// grid: NP/32 blocks. Absorbs prep: upper 128 threads regenerate yp per block
// (register sorting network, round-2-proven numerics) while lower 128 reduce
// per-channel min/max partials; then all 256 reduce the e-sum partials; then
// the proven contiguous-tile finish + pad-33 LDS transpose + coalesced store.
__global__ __launch_bounds__(256)
void pass2t(const float* __restrict__ xtile, const float* __restrict__ etile,
            const float* __restrict__ zf,
            const float* __restrict__ Wf1, const float* __restrict__ bf1,
            const float* __restrict__ Wf2, const float* __restrict__ bf2,
            const unsigned char* __restrict__ dirs_raw,
            const float* __restrict__ pminB, const float* __restrict__ pmaxB,
            const double* __restrict__ psum,
            float* __restrict__ out) {
    __shared__ float ytile[C_CH * 33];
    __shared__ float syp[C_CH * K_PWL];
    __shared__ float smin[C_CH], sinv[C_CH];
    __shared__ double sred[8];
    __shared__ float sstat[2];   // mean, 0.1/std
    __shared__ int is_i32;

    int t = threadIdx.x;
    int wave = t >> 6, lane = t & 63;

    if (t == 0) {
        // detect bool storage: int32 words (all 0/1) vs uint8 bytes
        const int* di = (const int*)dirs_raw;
        int ok = 1;
        for (int i = 0; i < 32; i++) { int v = di[i]; if (v != 0 && v != 1) ok = 0; }
        is_i32 = ok;
    }
    __syncthreads();

    if (t >= C_CH) {
        // yp regen for channel cc (identical math to verified prep; sorting
        // network = static indices -> registers)
        int cc = t - C_CH;
        float z[LAT];
        #pragma unroll
        for (int l = 0; l < LAT; l++) z[l] = zf[cc * LAT + l];
        float h[HID];
        #pragma unroll
        for (int j = 0; j < HID; j++) {
            float a = bf1[j];
            #pragma unroll
            for (int l = 0; l < LAT; l++) a = fmaf(z[l], Wf1[l * HID + j], a);
            h[j] = fast_tanh(a);
        }
        float p[K_PWL];
        #pragma unroll
        for (int k = 0; k < K_PWL; k++) {
            float a = bf2[k];
            #pragma unroll
            for (int j = 0; j < HID; j++) a = fmaf(h[j], Wf2[j * K_PWL + k], a);
            p[k] = fast_tanh(a);
        }
        #pragma unroll
        for (int ph = 0; ph < K_PWL; ph++) {
            #pragma unroll
            for (int k = (ph & 1); k + 1 < K_PWL; k += 2) {
                float lo = fminf(p[k], p[k + 1]);
                float hi = fmaxf(p[k], p[k + 1]);
                p[k] = lo; p[k + 1] = hi;
            }
        }
        int dir = is_i32 ? (((const int*)dirs_raw)[cc] != 0) : (dirs_raw[cc] != 0);
        #pragma unroll
        for (int k = 0; k < K_PWL; k++)
            syp[cc * K_PWL + k] = dir ? p[k] : p[K_PWL - 1 - k];
    } else {
        // per-channel min/max over QBLK partials
        float mn = 3.0e38f, mx = -3.0e38f;
        int base = t * QBLK;
        #pragma unroll 8
        for (int qq = 0; qq < QBLK; ++qq) {
            mn = fminf(mn, pminB[base + qq]);
            mx = fmaxf(mx, pmaxB[base + qq]);
        }
        smin[t] = mn;
        sinv[t] = __builtin_amdgcn_rcpf(mx - mn);
    }

    // global e sums over all C_CH*QBLK partials (all 256 threads)
    double S = 0.0, S2 = 0.0;
    for (int i = t; i < C_CH * QBLK; i += 256) {
        S  += psum[2 * i];
        S2 += psum[2 * i + 1];
    }
    #pragma unroll
    for (int o = 32; o > 0; o >>= 1) {
        S  += __shfl_down(S, o);
        S2 += __shfl_down(S2, o);
    }
    if (lane == 0) { sred[wave] = S; sred[4 + wave] = S2; }
    __syncthreads();
    if (t == 0) {
        S  = sred[0] + sred[1] + sred[2] + sred[3];
        S2 = sred[4] + sred[5] + sred[6] + sred[7];
        double M = (double)C_CH * NP;
        double mean = S / M;
        double var = (S2 - S * S / M) / (M - 1.0);
        sstat[0] = (float)mean;
        sstat[1] = (float)(0.1 / sqrt(var));
    }
    __syncthreads();

    const float INV_DENOM = 1.0f / (1.0f / 19.0f + 1e-7f);
    float mean = sstat[0], escale = sstat[1];
    size_t tbase = (size_t)blockIdx.x * (C_CH * 32);
    int n0 = blockIdx.x * 32;

    #pragma unroll
    for (int i = 0; i < 16; i++) {
        int idx = i * 256 + t;       // idx = c*32 + j  (contiguous tile read)
        int c = idx >> 5;
        int j = idx & 31;
        float x = xtile[tbase + idx];
        float e = etile[tbase + idx];
        float xn = (x - smin[c]) * sinv[c];
        int seg = (int)floorf(xn * 19.0f);
        seg = max(0, min(18, seg));
        float y0 = syp[c * K_PWL + seg];
        float y1 = syp[c * K_PWL + seg + 1];
        float y = fmaf((xn - (float)seg * (1.0f / 19.0f)) * INV_DENOM, y1 - y0, y0);
        y = fmaf(e - mean, escale, y);
        ytile[c * 33 + j] = y;
    }
    __syncthreads();
    #pragma unroll
    for (int i = 0; i < 16; i++) {
        int idx = i * 256 + t;
        int j = idx >> 7;
        int c = idx & 127;
        out[(size_t)(n0 + j) * C_CH + c] = ytile[c * 33 + j];
    }
}

extern "C" void kernel_launch(void* const* d_in, const int* in_sizes, int n_in,
                              void* d_out, int out_size, void* d_ws, size_t ws_size,
                              hipStream_t stream) {
    const float* zf  = (const float*)d_in[0];
    const float* zx  = (const float*)d_in[1];
    const float* ze  = (const float*)d_in[2];
    const float* Wx1 = (const float*)d_in[3];
    const float* bx1 = (const float*)d_in[4];
    const float* Wx2 = (const float*)d_in[5];
    const float* bx2 = (const float*)d_in[6];
    const float* We1 = (const float*)d_in[7];
    const float* be1 = (const float*)d_in[8];
    const float* We2 = (const float*)d_in[9];
    const float* be2 = (const float*)d_in[10];
    const float* Wf1 = (const float*)d_in[11];
    const float* bf1 = (const float*)d_in[12];
    const float* Wf2 = (const float*)d_in[13];
    const float* bf2 = (const float*)d_in[14];
    const unsigned char* dirs = (const unsigned char*)d_in[15];

    // workspace layout (doubles first for 8-byte alignment)
    double* psum  = (double*)d_ws;                        // [C*QBLK][2]
    float*  pminB = (float*)(psum + 2 * C_CH * QBLK);     // [C*QBLK]
    float*  pmaxB = pminB + C_CH * QBLK;                  // [C*QBLK]
    float*  xtile = pmaxB + C_CH * QBLK;                  // [NP/32][C][32]
    float*  etile = xtile + (size_t)C_CH * NP;            // [NP/32][C][32]

    hipLaunchKernelGGL(pass1t, dim3(QBLK, C_CH), dim3(256), 0, stream,
                       zx, ze, Wx1, bx1, Wx2, bx2, We1, be1, We2, be2,
                       xtile, etile, pminB, pmaxB, psum);
    hipLaunchKernelGGL(pass2t, dim3(NP / 32), dim3(256), 0, stream,
                       xtile, etile, zf, Wf1, bf1, Wf2, bf2, dirs,
                       pminB, pmaxB, psum, (float*)d_out);
}

// Round 5
// 334.701 us; speedup vs baseline: 1.8126x; 1.8126x over previous
//
#include <hip/hip_runtime.h>

#define C_CH  128
#define NP    32768
#define K_PWL 20
#define LAT   8
#define HID   8
#define PTS   4                      // points per thread in pass1tile (r0-proven)
#define QBLK  (NP / (256 * PTS))     // 32 partial-blocks per channel

__device__ __forceinline__ float fast_tanh(float x) {
    float e = __expf(2.0f * x);                         // v_mul + v_exp_f32
    return fmaf(-2.0f, __builtin_amdgcn_rcpf(e + 1.0f), 1.0f);
}

// grid: (QBLK, C). EXACT round-0 pass1 codegen (VGPR 68, zero spill, 110 us
// measured): inline MLP expressions, PTS=4 staged upfront, plain
// __launch_bounds__(256) -- NO min-waves arg (every min-waves attempt spilled:
// r3 (256,8)->budget 32, 384 MB scratch; r4 (256,4)+restructure->924 MB fetch).
// Only two edits vs r0: (a) stores go to blocked-transpose [NP/32][C][32];
// (b) atomic-free per-block partials (removes prep-init dependency).
__global__ __launch_bounds__(256)
void pass1tile(const float* __restrict__ zx, const float* __restrict__ ze,
               const float* __restrict__ Wx1, const float* __restrict__ bx1,
               const float* __restrict__ Wx2, const float* __restrict__ bx2,
               const float* __restrict__ We1, const float* __restrict__ be1,
               const float* __restrict__ We2, const float* __restrict__ be2,
               float* __restrict__ xtile, float* __restrict__ etile,
               float* __restrict__ pminB, float* __restrict__ pmaxB,
               double* __restrict__ psum) {
    // weights in LDS: Wx1[64] bx1[8] Wx2[8] bx2[1] We1[64] be1[8] We2[8] be2[1]
    __shared__ float sw[162];
    int t = threadIdx.x;
    if (t < 64)       sw[t] = Wx1[t];
    else if (t < 72)  sw[t] = bx1[t - 64];
    else if (t < 80)  sw[t] = Wx2[t - 72];
    else if (t == 80) sw[80] = bx2[0];
    else if (t < 145) sw[t] = We1[t - 81];
    else if (t < 153) sw[t] = be1[t - 145];
    else if (t < 161) sw[t] = We2[t - 153];
    else if (t == 161) sw[161] = be2[0];
    __syncthreads();

    int c = blockIdx.y;
    int n0 = blockIdx.x * (256 * PTS) + t;
    size_t row = (size_t)c * NP;
    const float4* zx4 = (const float4*)(zx + row * LAT);
    const float4* ze4 = (const float4*)(ze + row * LAT);

    float4 ax[PTS][2], ae[PTS][2];
    #pragma unroll
    for (int k = 0; k < PTS; k++) {
        int n = n0 + k * 256;
        ax[k][0] = zx4[2 * n];  ax[k][1] = zx4[2 * n + 1];
        ae[k][0] = ze4[2 * n];  ae[k][1] = ze4[2 * n + 1];
    }

    float xv[PTS], ev[PTS];
    #pragma unroll
    for (int k = 0; k < PTS; k++) {
        float acc = sw[80];
        #pragma unroll
        for (int j = 0; j < HID; j++) {
            float hh = sw[64 + j];
            hh = fmaf(ax[k][0].x, sw[0 * 8 + j], hh);
            hh = fmaf(ax[k][0].y, sw[1 * 8 + j], hh);
            hh = fmaf(ax[k][0].z, sw[2 * 8 + j], hh);
            hh = fmaf(ax[k][0].w, sw[3 * 8 + j], hh);
            hh = fmaf(ax[k][1].x, sw[4 * 8 + j], hh);
            hh = fmaf(ax[k][1].y, sw[5 * 8 + j], hh);
            hh = fmaf(ax[k][1].z, sw[6 * 8 + j], hh);
            hh = fmaf(ax[k][1].w, sw[7 * 8 + j], hh);
            acc = fmaf(fast_tanh(hh), sw[72 + j], acc);
        }
        xv[k] = fast_tanh(acc);
    }
    #pragma unroll
    for (int k = 0; k < PTS; k++) {
        float acc = sw[161];
        #pragma unroll
        for (int j = 0; j < HID; j++) {
            float hh = sw[145 + j];
            hh = fmaf(ae[k][0].x, sw[81 + 0 * 8 + j], hh);
            hh = fmaf(ae[k][0].y, sw[81 + 1 * 8 + j], hh);
            hh = fmaf(ae[k][0].z, sw[81 + 2 * 8 + j], hh);
            hh = fmaf(ae[k][0].w, sw[81 + 3 * 8 + j], hh);
            hh = fmaf(ae[k][1].x, sw[81 + 4 * 8 + j], hh);
            hh = fmaf(ae[k][1].y, sw[81 + 5 * 8 + j], hh);
            hh = fmaf(ae[k][1].z, sw[81 + 6 * 8 + j], hh);
            hh = fmaf(ae[k][1].w, sw[81 + 7 * 8 + j], hh);
            acc = fmaf(fast_tanh(hh), sw[153 + j], acc);
        }
        ev[k] = fast_tanh(acc);
    }

    float mn = xv[0], mx = xv[0], s = 0.f, s2 = 0.f;
    int cbase = c * 32;
    #pragma unroll
    for (int k = 0; k < PTS; k++) {
        int n = n0 + k * 256;
        int addr = (n >> 5) * (C_CH * 32) + cbase + (n & 31);   // tile layout
        xtile[addr] = xv[k];
        etile[addr] = ev[k];
        mn = fminf(mn, xv[k]); mx = fmaxf(mx, xv[k]);
        s += ev[k]; s2 += ev[k] * ev[k];
    }

    #pragma unroll
    for (int o = 32; o > 0; o >>= 1) {
        mn = fminf(mn, __shfl_down(mn, o));
        mx = fmaxf(mx, __shfl_down(mx, o));
        s += __shfl_down(s, o);
        s2 += __shfl_down(s2, o);
    }
    __shared__ float rmn[4], rmx[4], rs[4], rs2[4];
    int wave = t >> 6, lane = t & 63;
    if (lane == 0) { rmn[wave] = mn; rmx[wave] = mx; rs[wave] = s; rs2[wave] = s2; }
    __syncthreads();
    if (t == 0) {
        for (int w = 1; w < 4; w++) {
            mn = fminf(mn, rmn[w]); mx = fmaxf(mx, rmx[w]);
        }
        int slot = c * QBLK + blockIdx.x;
        pminB[slot] = mn;
        pmaxB[slot] = mx;
        psum[2 * slot]     = (double)rs[0] + (double)rs[1] + (double)rs[2] + (double)rs[3];
        psum[2 * slot + 1] = (double)rs2[0] + (double)rs2[1] + (double)rs2[2] + (double)rs2[3];
    }
}

// grid: NP/32 blocks. Absorbs prep: upper 128 threads regenerate yp per block
// (register sorting network) while lower 128 reduce per-channel min/max
// partials; all 256 reduce e-sum partials; then contiguous float4 tile read,
// PWL + e-standardize, pad-33 LDS transpose, coalesced [N,C] store.
__global__ __launch_bounds__(256)
void pass2t(const float* __restrict__ xtile, const float* __restrict__ etile,
            const float* __restrict__ zf,
            const float* __restrict__ Wf1, const float* __restrict__ bf1,
            const float* __restrict__ Wf2, const float* __restrict__ bf2,
            const unsigned char* __restrict__ dirs_raw,
            const float* __restrict__ pminB, const float* __restrict__ pmaxB,
            const double* __restrict__ psum,
            float* __restrict__ out) {
    __shared__ float ytile[C_CH * 33];
    __shared__ float syp[C_CH * K_PWL];
    __shared__ float smin[C_CH], sinv[C_CH];
    __shared__ double sred[8];
    __shared__ float sstat[2];   // mean, 0.1/std
    __shared__ int is_i32;

    int t = threadIdx.x;
    int wave = t >> 6, lane = t & 63;

    if (t == 0) {
        // detect bool storage: int32 words (all 0/1) vs uint8 bytes
        const int* di = (const int*)dirs_raw;
        int ok = 1;
        for (int i = 0; i < 32; i++) { int v = di[i]; if (v != 0 && v != 1) ok = 0; }
        is_i32 = ok;
    }
    __syncthreads();

    if (t >= C_CH) {
        // yp regen for channel cc (identical math to verified prep; sorting
        // network = static indices -> registers)
        int cc = t - C_CH;
        float z[LAT];
        #pragma unroll
        for (int l = 0; l < LAT; l++) z[l] = zf[cc * LAT + l];
        float h[HID];
        #pragma unroll
        for (int j = 0; j < HID; j++) {
            float a = bf1[j];
            #pragma unroll
            for (int l = 0; l < LAT; l++) a = fmaf(z[l], Wf1[l * HID + j], a);
            h[j] = fast_tanh(a);
        }
        float p[K_PWL];
        #pragma unroll
        for (int k = 0; k < K_PWL; k++) {
            float a = bf2[k];
            #pragma unroll
            for (int j = 0; j < HID; j++) a = fmaf(h[j], Wf2[j * K_PWL + k], a);
            p[k] = fast_tanh(a);
        }
        #pragma unroll
        for (int ph = 0; ph < K_PWL; ph++) {
            #pragma unroll
            for (int k = (ph & 1); k + 1 < K_PWL; k += 2) {
                float lo = fminf(p[k], p[k + 1]);
                float hi = fmaxf(p[k], p[k + 1]);
                p[k] = lo; p[k + 1] = hi;
            }
        }
        int dir = is_i32 ? (((const int*)dirs_raw)[cc] != 0) : (dirs_raw[cc] != 0);
        #pragma unroll
        for (int k = 0; k < K_PWL; k++)
            syp[cc * K_PWL + k] = dir ? p[k] : p[K_PWL - 1 - k];
    } else {
        // per-channel min/max over QBLK partials
        float mn = 3.0e38f, mx = -3.0e38f;
        int base = t * QBLK;
        #pragma unroll 8
        for (int qq = 0; qq < QBLK; ++qq) {
            mn = fminf(mn, pminB[base + qq]);
            mx = fmaxf(mx, pmaxB[base + qq]);
        }
        smin[t] = mn;
        sinv[t] = __builtin_amdgcn_rcpf(mx - mn);
    }

    // global e sums over all C_CH*QBLK partials (all 256 threads)
    double S = 0.0, S2 = 0.0;
    for (int i = t; i < C_CH * QBLK; i += 256) {
        S  += psum[2 * i];
        S2 += psum[2 * i + 1];
    }
    #pragma unroll
    for (int o = 32; o > 0; o >>= 1) {
        S  += __shfl_down(S, o);
        S2 += __shfl_down(S2, o);
    }
    if (lane == 0) { sred[wave] = S; sred[4 + wave] = S2; }
    __syncthreads();
    if (t == 0) {
        S  = sred[0] + sred[1] + sred[2] + sred[3];
        S2 = sred[4] + sred[5] + sred[6] + sred[7];
        double M = (double)C_CH * NP;
        double mean = S / M;
        double var = (S2 - S * S / M) / (M - 1.0);
        sstat[0] = (float)mean;
        sstat[1] = (float)(0.1 / sqrt(var));
    }
    __syncthreads();

    const float INV_DENOM = 1.0f / (1.0f / 19.0f + 1e-7f);
    float mean = sstat[0], escale = sstat[1];
    size_t tbase = (size_t)blockIdx.x * (C_CH * 32);
    int n0 = blockIdx.x * 32;

    // contiguous float4 tile read (G13), 4 elems/thread/iter
    const float4* xt4 = (const float4*)(xtile + tbase);
    const float4* et4 = (const float4*)(etile + tbase);
    #pragma unroll
    for (int i = 0; i < 4; i++) {
        int i4 = i * 256 + t;            // float4 index within tile (0..1023)
        float4 xq = xt4[i4];
        float4 eq = et4[i4];
        int c = i4 >> 3;                 // 8 float4 per channel row
        int j0 = (i4 & 7) * 4;
        float sm = smin[c], si = sinv[c];
        int sb = c * K_PWL;
        int yb = c * 33 + j0;
        {
            float xn = (xq.x - sm) * si;
            int seg = (int)floorf(xn * 19.0f); seg = max(0, min(18, seg));
            float y0 = syp[sb + seg], y1 = syp[sb + seg + 1];
            float y = fmaf((xn - (float)seg * (1.0f / 19.0f)) * INV_DENOM, y1 - y0, y0);
            ytile[yb + 0] = fmaf(eq.x - mean, escale, y);
        }
        {
            float xn = (xq.y - sm) * si;
            int seg = (int)floorf(xn * 19.0f); seg = max(0, min(18, seg));
            float y0 = syp[sb + seg], y1 = syp[sb + seg + 1];
            float y = fmaf((xn - (float)seg * (1.0f / 19.0f)) * INV_DENOM, y1 - y0, y0);
            ytile[yb + 1] = fmaf(eq.y - mean, escale, y);
        }
        {
            float xn = (xq.z - sm) * si;
            int seg = (int)floorf(xn * 19.0f); seg = max(0, min(18, seg));
            float y0 = syp[sb + seg], y1 = syp[sb + seg + 1];
            float y = fmaf((xn - (float)seg * (1.0f / 19.0f)) * INV_DENOM, y1 - y0, y0);
            ytile[yb + 2] = fmaf(eq.z - mean, escale, y);
        }
        {
            float xn = (xq.w - sm) * si;
            int seg = (int)floorf(xn * 19.0f); seg = max(0, min(18, seg));
            float y0 = syp[sb + seg], y1 = syp[sb + seg + 1];
            float y = fmaf((xn - (float)seg * (1.0f / 19.0f)) * INV_DENOM, y1 - y0, y0);
            ytile[yb + 3] = fmaf(eq.w - mean, escale, y);
        }
    }
    __syncthreads();
    #pragma unroll
    for (int i = 0; i < 16; i++) {
        int idx = i * 256 + t;
        int j = idx >> 7;
        int c = idx & 127;
        out[(size_t)(n0 + j) * C_CH + c] = ytile[c * 33 + j];
    }
}

extern "C" void kernel_launch(void* const* d_in, const int* in_sizes, int n_in,
                              void* d_out, int out_size, void* d_ws, size_t ws_size,
                              hipStream_t stream) {
    const float* zf  = (const float*)d_in[0];
    const float* zx  = (const float*)d_in[1];
    const float* ze  = (const float*)d_in[2];
    const float* Wx1 = (const float*)d_in[3];
    const float* bx1 = (const float*)d_in[4];
    const float* Wx2 = (const float*)d_in[5];
    const float* bx2 = (const float*)d_in[6];
    const float* We1 = (const float*)d_in[7];
    const float* be1 = (const float*)d_in[8];
    const float* We2 = (const float*)d_in[9];
    const float* be2 = (const float*)d_in[10];
    const float* Wf1 = (const float*)d_in[11];
    const float* bf1 = (const float*)d_in[12];
    const float* Wf2 = (const float*)d_in[13];
    const float* bf2 = (const float*)d_in[14];
    const unsigned char* dirs = (const unsigned char*)d_in[15];

    // workspace layout (doubles first for 8-byte alignment)
    double* psum  = (double*)d_ws;                        // [C*QBLK][2]
    float*  pminB = (float*)(psum + 2 * C_CH * QBLK);     // [C*QBLK]
    float*  pmaxB = pminB + C_CH * QBLK;                  // [C*QBLK]
    float*  xtile = pmaxB + C_CH * QBLK;                  // [NP/32][C][32]
    float*  etile = xtile + (size_t)C_CH * NP;            // [NP/32][C][32]

    hipLaunchKernelGGL(pass1tile, dim3(QBLK, C_CH), dim3(256), 0, stream,
                       zx, ze, Wx1, bx1, Wx2, bx2, We1, be1, We2, be2,
                       xtile, etile, pminB, pmaxB, psum);
    hipLaunchKernelGGL(pass2t, dim3(NP / 32), dim3(256), 0, stream,
                       xtile, etile, zf, Wf1, bf1, Wf2, bf2, dirs,
                       pminB, pmaxB, psum, (float*)d_out);
}